// Round 4
// baseline (460.426 us; speedup 1.0000x reference)
//
#include <hip/hip_runtime.h>
#include <hip/hip_cooperative_groups.h>
#include <stdint.h>

#pragma clang fp contract(off)

namespace cg = cooperative_groups;

#define NA 10
#define LL 4096
#define NB 4
#define NSEL (LL * NA)        // 40960 proposals per image
#define PRE2 2048             // NMS candidate window (prefix-stable: 300 kept << 2048)
#define POST_NMS 300
#define CAND 4096             // candidate buffer (threshold overshoot bound)
#define NHB 65536             // 16-bit-prefix histogram buckets
#define TWORDS 33792          // col-major mask words per image: 64 * sum_{w=0..31}(w+1)
#define GRID 320              // NB*NSEL/512 blocks; 2/CU co-residency (65.4KB LDS union)
#define NTHR 256

__constant__ float c_WS[NA] = {16.f, 32.f, 40.f, 48.f, 64.f, 72.f, 80.f, 96.f, 112.f, 128.f};

// async global->LDS DMA: per-lane 16B from g (per-lane addr), lands at uniform dst + lane*16
__device__ inline void gload_lds16(const void* g, void* l) {
    __builtin_amdgcn_global_load_lds(
        (const __attribute__((address_space(1))) unsigned*)g,
        (__attribute__((address_space(3))) unsigned*)l, 16, 0, 0);
}

// ---- LDS phase union (max member: reduce's 64KB colbuf) ----
struct SPrep { unsigned shist[64]; };
struct SComp { unsigned coarse[64]; unsigned wsum[4]; unsigned sAfter; int sC;
               unsigned skmin; int woff[4]; int sbase; };
struct SRank { unsigned long long keys[CAND]; unsigned part[4][64][4]; };
struct SMask { float2 lj[256]; };
struct SRed  { unsigned long long colbuf[4][2048]; unsigned long long Kl[32];
               int sKl[POST_NMS]; int keptCnt; };
union SMem { SPrep prep; SComp comp; SRank rank; SMask mask; SRed red; };

// ===================== single fused cooperative kernel =====================
// Round-3 post-mortem: per-kernel cost models sum to ~30us vs 95.5 measured ->
// ~6-9us per graph node x 7 nodes is the real remaining bottleneck. Fuse all
// phases into ONE cooperative launch; grid.sync() + explicit __threadfence()
// (agent fence = buffer_wbl2/buffer_inv on gfx950) replaces the cross-XCD
// visibility that kernel boundaries used to provide.
__global__ __launch_bounds__(NTHR, 2) void k_fused(
    const float* __restrict__ scores, const float* __restrict__ deltas,
    unsigned long long* __restrict__ packed, float2* __restrict__ prop,
    float2* __restrict__ srt, unsigned long long* __restrict__ maskT,
    unsigned* __restrict__ ghist, unsigned* __restrict__ gcoarse,
    int* __restrict__ gcnt, unsigned long long* __restrict__ cand,
    float* __restrict__ out)
{
    cg::grid_group grid = cg::this_grid();
    __shared__ __align__(16) SMem sm;
    const int tid  = threadIdx.x;
    const int bid  = blockIdx.x;
    const int lane = tid & 63;
    const int wv   = tid >> 6;

    // ---------------- Phase 0: zero ghist+gcoarse+gcnt (contiguous region) ----------------
    {
        const int NZ = NB * NHB + NB * 64 + NB;          // 262404 u32
        for (int i = bid * NTHR + tid; i < NZ; i += GRID * NTHR) ghist[i] = 0u;
    }
    __threadfence(); grid.sync(); __threadfence();

    // ---------------- Phase 1: decode (2 elems/thread) + keys + hist + coarse hist ----------------
    {
        if (tid < 64) sm.prep.shist[tid] = 0;
        __syncthreads();

        const int g = bid * NTHR + tid;
        const int e = g << 1;               // 512 elements per block; 80 blocks per image
        const int b = e / NSEL;
        const int r = e - b * NSEL;         // r = a*4096 + l, l even
        const int a = r >> 12;
        const int l = r & 4095;

        const float w = c_WS[a];
        const float2 sc2 = *(const float2*)&scores[((b * 20 + 10 + a) << 12) + l];
        const float2 d02 = *(const float2*)&deltas[((b * 20 + 2 * a) << 12) + l];
        const float2 d12 = *(const float2*)&deltas[((b * 20 + 2 * a + 1) << 12) + l];

        unsigned key0, key1;
        float4 pr;
        {
            float ctr = (float)(8 * l + 4);
            float pc = d02.x * w + ctr;                // contract(off): mul then add, matches numpy
            float pl = expf(d12.x) * w;
            float x1 = fminf(fmaxf(pc - 0.5f * pl, 0.0f), 32767.0f);
            float x2 = fminf(fmaxf(pc + 0.5f * pl, 0.0f), 32767.0f);
            float sc = sc2.x;
            if (x2 - x1 + 1.0f < 8.0f) sc = 0.0f;
            unsigned u = __float_as_uint(sc);
            key0 = (u & 0x80000000u) ? ~u : (u | 0x80000000u);
            pr.x = x1; pr.y = x2;
        }
        {
            float ctr = (float)(8 * (l + 1) + 4);
            float pc = d02.y * w + ctr;
            float pl = expf(d12.y) * w;
            float x1 = fminf(fmaxf(pc - 0.5f * pl, 0.0f), 32767.0f);
            float x2 = fminf(fmaxf(pc + 0.5f * pl, 0.0f), 32767.0f);
            float sc = sc2.y;
            if (x2 - x1 + 1.0f < 8.0f) sc = 0.0f;
            unsigned u = __float_as_uint(sc);
            key1 = (u & 0x80000000u) ? ~u : (u | 0x80000000u);
            pr.z = x1; pr.w = x2;
        }

        const unsigned long long p0 =
            ((unsigned long long)key0 << 32) | (unsigned)(0xFFFFFFFFu - (unsigned)(l * NA + a));
        const unsigned long long p1 =
            ((unsigned long long)key1 << 32) | (unsigned)(0xFFFFFFFFu - (unsigned)((l + 1) * NA + a));

        *(ulonglong2*)&packed[b * NSEL + r] = make_ulonglong2(p0, p1);
        *(float4*)&prop[b * NSEL + r] = pr;

        atomicAdd(&ghist[b * NHB + (key0 >> 16)], 1u);
        atomicAdd(&ghist[b * NHB + (key1 >> 16)], 1u);
        const unsigned c0 = key0 >> 26, c1 = key1 >> 26;
        if (c0 == c1) atomicAdd(&sm.prep.shist[c0], 2u);
        else { atomicAdd(&sm.prep.shist[c0], 1u); atomicAdd(&sm.prep.shist[c1], 1u); }

        __syncthreads();
        if (tid < 64) {
            unsigned v = sm.prep.shist[tid];
            if (v) atomicAdd(&gcoarse[(b << 6) + tid], v);   // b uniform per block
        }
    }
    __threadfence(); grid.sync(); __threadfence();

    // ---------------- Phase 2: per-block kmin (coarse+fine suffix scans) + compact ----------------
    {
        const int b = bid / 80;
        const unsigned* gh = ghist + b * NHB;

        if (tid < 64) sm.comp.coarse[tid] = gcoarse[(b << 6) + tid];
        __syncthreads();

        // coarse suffix scan (wave 0): find crossing chunk
        if (tid < 64) {
            unsigned v = sm.comp.coarse[tid];
            unsigned inc = v;
            #pragma unroll
            for (int d = 1; d < 64; d <<= 1) {
                unsigned u = (unsigned)__shfl_down((int)inc, d, 64);
                if (tid + d < 64) inc += u;
            }
            if (inc >= (unsigned)PRE2 && (inc - v) < (unsigned)PRE2) { sm.comp.sC = tid; sm.comp.sAfter = inc - v; }
        }
        __syncthreads();

        // fine scan: 256 threads x 4 consecutive buckets of crossing chunk
        {
            const int C = sm.comp.sC;
            const unsigned after = sm.comp.sAfter;
            const uint4 l4 = *(const uint4*)&gh[(C << 10) + (tid << 2)];
            const unsigned s4 = l4.x + l4.y + l4.z + l4.w;
            unsigned inc = s4;
            #pragma unroll
            for (int d = 1; d < 64; d <<= 1) {
                unsigned u = (unsigned)__shfl_down((int)inc, d, 64);
                if (lane + d < 64) inc += u;
            }
            if (lane == 0) sm.comp.wsum[wv] = inc;
            __syncthreads();
            if (tid < 4) {
                unsigned t = sm.comp.wsum[tid];
                unsigned winc = t;
                #pragma unroll
                for (int d = 1; d < 4; d <<= 1) {
                    unsigned u = (unsigned)__shfl_down((int)winc, d, 64);
                    if (tid + d < 4) winc += u;
                }
                sm.comp.wsum[tid] = winc - t;          // waves strictly after tid
            }
            __syncthreads();
            const unsigned gIncl = inc + sm.comp.wsum[wv] + after;  // suffix incl my 4-bucket group
            const unsigned base = gIncl - s4;                        // strictly after my group
            const unsigned t3 = base + l4.w;
            const unsigned t2 = t3 + l4.z;
            const unsigned t1 = t2 + l4.y;
            const unsigned t0 = t1 + l4.x;
            const unsigned bx = (unsigned)((C << 10) + (tid << 2));
            if (t0 >= (unsigned)PRE2 && t0 - l4.x < (unsigned)PRE2) sm.comp.skmin = (bx + 0) << 16;
            if (t1 >= (unsigned)PRE2 && t1 - l4.y < (unsigned)PRE2) sm.comp.skmin = (bx + 1) << 16;
            if (t2 >= (unsigned)PRE2 && t2 - l4.z < (unsigned)PRE2) sm.comp.skmin = (bx + 2) << 16;
            if (t3 >= (unsigned)PRE2 && t3 - l4.w < (unsigned)PRE2) sm.comp.skmin = (bx + 3) << 16;
        }
        __syncthreads();
        const unsigned kmin = sm.comp.skmin;

        // compact 512 elements (2/thread), unordered (rank restores exact order)
        const int rr = (bid - b * 80) * 512 + (tid << 1);
        const ulonglong2 pp = *(const ulonglong2*)&packed[b * NSEL + rr];
        const bool pd0 = ((unsigned)(pp.x >> 32) >= kmin);
        const bool pd1 = ((unsigned)(pp.y >> 32) >= kmin);
        const unsigned long long m0 = __ballot(pd0);
        const unsigned long long m1 = __ballot(pd1);
        if (lane == 0) sm.comp.woff[wv] = (int)(__popcll(m0) + __popcll(m1));
        __syncthreads();
        if (tid == 0) {
            int a0 = sm.comp.woff[0], a1 = sm.comp.woff[1], a2 = sm.comp.woff[2], a3 = sm.comp.woff[3];
            sm.comp.sbase = atomicAdd(&gcnt[b], a0 + a1 + a2 + a3);   // one global atomic per block
            sm.comp.woff[0] = 0; sm.comp.woff[1] = a0;
            sm.comp.woff[2] = a0 + a1; sm.comp.woff[3] = a0 + a1 + a2;
        }
        __syncthreads();
        const int basep = sm.comp.sbase + sm.comp.woff[wv];
        const unsigned long long below = (1ULL << lane) - 1ULL;
        if (pd0) {
            int pos = basep + (int)__popcll(m0 & below);
            if (pos < CAND) cand[b * CAND + pos] = pp.x;
        }
        if (pd1) {
            int pos = basep + (int)__popcll(m0) + (int)__popcll(m1 & below);
            if (pos < CAND) cand[b * CAND + pos] = pp.y;
        }
    }
    __threadfence(); grid.sync(); __threadfence();

    // ---------------- Phase 3: rank-scatter (blocks 0..63), LDS-staged ----------------
    // rank_i = #{j : key_j > key_i}: exact descending-sort position (keys unique).
    if (bid < 64) {
        const int b = bid >> 4;
        const int ib = (bid & 15) << 8;
        const int n0 = gcnt[b];
        const int n = n0 < CAND ? n0 : CAND;
        if (ib < n) {                                  // block-uniform
            const unsigned long long* cb = cand + b * CAND;
            const int nP = (n + 7) & ~7;
            for (int j = tid; j < nP; j += 256)
                sm.rank.keys[j] = (j < n) ? cb[j] : 0ULL;
            __syncthreads();

            const int i0 = ib + (lane << 2);
            const unsigned long long k0 = sm.rank.keys[i0 + 0];
            const unsigned long long k1 = sm.rank.keys[i0 + 1];
            const unsigned long long k2 = sm.rank.keys[i0 + 2];
            const unsigned long long k3 = sm.rank.keys[i0 + 3];

            const int q = nP >> 2;
            const ulonglong2* keys2 = (const ulonglong2*)sm.rank.keys;
            const int pb = (wv * q) >> 1;
            const int pn = q >> 1;
            unsigned r0 = 0, r1 = 0, r2 = 0, r3 = 0;
            #pragma unroll 4
            for (int p = 0; p < pn; ++p) {
                ulonglong2 kj = keys2[pb + p];         // broadcast: conflict-free
                r0 += (kj.x > k0); r0 += (kj.y > k0);
                r1 += (kj.x > k1); r1 += (kj.y > k1);
                r2 += (kj.x > k2); r2 += (kj.y > k2);
                r3 += (kj.x > k3); r3 += (kj.y > k3);
            }
            sm.rank.part[wv][lane][0] = r0; sm.rank.part[wv][lane][1] = r1;
            sm.rank.part[wv][lane][2] = r2; sm.rank.part[wv][lane][3] = r3;
            __syncthreads();

            const int ig = ib + tid;
            if (ig < n) {
                const int l_ = tid >> 2, c_ = tid & 3;
                unsigned r = sm.rank.part[0][l_][c_] + sm.rank.part[1][l_][c_]
                           + sm.rank.part[2][l_][c_] + sm.rank.part[3][l_][c_];
                if (r < PRE2) {
                    unsigned long long k = sm.rank.keys[ig];
                    unsigned idx_ = 0xFFFFFFFFu - (unsigned)k;
                    unsigned a_ = idx_ % 10u, l2_ = idx_ / 10u;
                    srt[b * PRE2 + r] = prop[b * NSEL + (a_ << 12) + l2_];
                }
            }
        }
    }
    __threadfence(); grid.sync(); __threadfence();

    // ---------------- Phase 4: COLUMN-major suppression mask (576 triangular units) ----------------
    for (int u = bid; u < 144 * NB; u += GRID) {
        const int b = u / 144;
        const int t144 = u - b * 144;
        int wj = 0, acc = 0;                       // decode triangular unit -> (wj, g)
        while (acc + (wj >> 2) + 1 <= t144) { acc += (wj >> 2) + 1; ++wj; }
        const int g = t144 - acc;

        __syncthreads();                           // protect lj reuse across units
        sm.mask.lj[tid] = srt[b * PRE2 + (g << 8) + tid];
        __syncthreads();

        const int wi = (g << 2) + (tid >> 6);
        if (wi <= wj) {
            const int j = (wj << 6) + (tid & 63);
            const float2 pj = srt[b * PRE2 + j];
            const float ljn = pj.y - pj.x + 1.0f;
            unsigned long long bits = 0ULL;
            const int lbase = (tid >> 6) * 64;
            const int ibase = wi << 6;
            #pragma unroll 4
            for (int t = 0; t < 64; ++t) {
                float2 pv = sm.mask.lj[lbase + t];
                float inter = fminf(pj.y, pv.y) - fmaxf(pj.x, pv.x) + 1.0f;
                bool sup = false;
                if (inter > 0.0f) {
                    float uni = ljn + (pv.y - pv.x + 1.0f) - inter;
                    sup = (inter / uni) > 0.7f;    // IEEE div, same rounding as reference
                }
                if ((ibase + t < j) && sup) bits |= (1ULL << t);
            }
            maskT[(size_t)b * TWORDS + (size_t)((wj * (wj + 1) / 2) + wi) * 64 + (tid & 63)] = bits;
        }
    }
    __threadfence(); grid.sync(); __threadfence();

    // ---------------- Phase 5: single-wave greedy, depth-4 column prefetch (blocks 0..3) ----------------
    if (bid >= NB) return;
    {
        const int b = bid;
        const unsigned long long* mTb = maskT + (size_t)b * TWORDS;

        if (tid < 64) {
            auto stage = [&](int wvv, int buf) {       // fixed 16 KB stage (16 VMEM ops)
                const char* src = (const char*)(mTb + (size_t)(wvv * (wvv + 1) / 2) * 64) + lane * 16;
                char* dst = (char*)(&sm.red.colbuf[buf][0]);
                #pragma unroll
                for (int k = 0; k < 16; ++k)
                    gload_lds16(src + k * 1024, dst + k * 1024);
            };
            stage(0, 0); stage(1, 1); stage(2, 2); stage(3, 3);

            int kept = 0;
            bool done = false;
            for (int w = 0; w < 32 && !done; ++w) {
                asm volatile("s_waitcnt vmcnt(48)" ::: "memory");   // 3 stages stay in flight
                __builtin_amdgcn_sched_barrier(0);

                const unsigned long long* cw = &sm.red.colbuf[w & 3][0];
                unsigned long long SUP = 0ULL;
                for (int wi = 0; wi < w; ++wi)
                    SUP |= sm.red.Kl[wi] & cw[(wi << 6) + lane];
                unsigned long long x = cw[(w << 6) + lane];

                unsigned long long avail = ~__ballot(SUP != 0ULL);
                asm volatile("s_waitcnt lgkmcnt(0)" ::: "memory");
                __builtin_amdgcn_sched_barrier(0);
                asm volatile("" : "+v"(x));
                { int nx = w + 4; stage(nx < 31 ? nx : 31, nx & 3); }

                unsigned long long keptw = 0ULL;
                while (avail) {
                    int j = __ffsll((long long)avail) - 1;   // wave-uniform
                    if (lane == 0) sm.red.sKl[kept] = (w << 6) + j;
                    kept++; keptw |= (1ULL << j);
                    if (kept >= POST_NMS) { done = true; break; }
                    unsigned long long supb = __ballot(((x >> j) & 1ULL) != 0ULL);
                    avail &= ~supb;
                    avail &= ~(1ULL << j);
                }
                if (lane == 0) sm.red.Kl[w] = keptw;
            }
            if (lane == 0) sm.red.keptCnt = kept;
        }
        __syncthreads();
        const int keptN = sm.red.keptCnt;
        for (int t = tid; t < POST_NMS; t += NTHR) {
            float x1 = 0.0f, x2 = 0.0f;
            if (t < keptN) {
                float2 pv = srt[b * PRE2 + sm.red.sKl[t]];
                x1 = pv.x; x2 = pv.y;
            }
            float* o = out + (size_t)(b * POST_NMS + t) * 3;
            o[0] = (float)b; o[1] = x1; o[2] = x2;
        }
    }
}

extern "C" void kernel_launch(void* const* d_in, const int* in_sizes, int n_in,
                              void* d_out, int out_size, void* d_ws, size_t ws_size,
                              hipStream_t stream) {
    const float* scores = (const float*)d_in[0];
    const float* deltas = (const float*)d_in[1];
    float* out = (float*)d_out;

    char* ws = (char*)d_ws;
    unsigned long long* packed   = (unsigned long long*)ws;                 // 1,310,720 B
    float2* prop                 = (float2*)(ws + 1310720);                 // 1,310,720 B
    float2* srt                  = (float2*)(ws + 2621440);                 //    65,536 B
    unsigned long long* maskT    = (unsigned long long*)(ws + 2686976);     // 1,081,344 B
    unsigned* ghist              = (unsigned*)(ws + 3768320);               // 1,048,576 B
    unsigned* gcoarse            = (unsigned*)(ws + 4816896);               //     1,024 B  (contiguous after ghist)
    int* gcnt                    = (int*)(ws + 4817920);                    //        16 B  (contiguous after gcoarse)
    unsigned long long* cand     = (unsigned long long*)(ws + 4817936);     //   131,072 B  (16B aligned; no aliasing)

    void* args[] = {
        (void*)&scores, (void*)&deltas, (void*)&packed, (void*)&prop,
        (void*)&srt, (void*)&maskT, (void*)&ghist, (void*)&gcoarse,
        (void*)&gcnt, (void*)&cand, (void*)&out
    };
    hipLaunchCooperativeKernel((const void*)k_fused, dim3(GRID), dim3(NTHR), args, 0, stream);
}

// Round 5
// 85.143 us; speedup vs baseline: 5.4076x; 5.4076x over previous
//
#include <hip/hip_runtime.h>
#include <stdint.h>

#pragma clang fp contract(off)

#define NA 10
#define LL 4096
#define NB 4
#define NSEL (LL * NA)        // 40960 proposals per image
#define PRE2 2048             // NMS candidate window (prefix-stable: 300 kept << 2048)
#define POST_NMS 300
#define CAND 4096             // candidate buffer (threshold overshoot bound)
#define TWORDS 33792          // col-major mask words per image: 64 * sum_{w=0..31}(w+1)

__constant__ float c_WS[NA] = {16.f, 32.f, 40.f, 48.f, 64.f, 72.f, 80.f, 96.f, 112.f, 128.f};

// async global->LDS DMA: per-lane 16B from g (per-lane addr), lands at uniform dst + lane*16
__device__ inline void gload_lds16(const void* g, void* l) {
    __builtin_amdgcn_global_load_lds(
        (const __attribute__((address_space(1))) unsigned*)g,
        (__attribute__((address_space(3))) unsigned*)l, 16, 0, 0);
}

// ---------------- Kernel 1: pure decode (2 elems/thread) + key pack ----------------
// Round-4 post-mortem: cooperative fusion (460us) was killed by per-wave agent fences
// (buffer_wbl2/inv = full L2 walk x 12800). Back to multi-kernel; histogram moved to
// k_select's LDS, so prep is now pure decode: no atomics, no global hist.
__global__ __launch_bounds__(256) void k_prep(const float* __restrict__ scores,
                                              const float* __restrict__ deltas,
                                              unsigned long long* __restrict__ packed,
                                              float2* __restrict__ prop) {
    const int tid = threadIdx.x;
    const int g = blockIdx.x * 256 + tid;
    const int e = g << 1;               // 512 elements per block; 80 blocks per image
    const int b = e / NSEL;
    const int r = e - b * NSEL;         // r = a*4096 + l, l even
    const int a = r >> 12;
    const int l = r & 4095;

    const float w = c_WS[a];
    const float2 sc2 = *(const float2*)&scores[((b * 20 + 10 + a) << 12) + l];
    const float2 d02 = *(const float2*)&deltas[((b * 20 + 2 * a) << 12) + l];
    const float2 d12 = *(const float2*)&deltas[((b * 20 + 2 * a + 1) << 12) + l];

    unsigned key0, key1;
    float4 pr;
    {
        float ctr = (float)(8 * l + 4);
        float pc = d02.x * w + ctr;                // contract(off): mul then add, matches numpy
        float pl = expf(d12.x) * w;
        float x1 = fminf(fmaxf(pc - 0.5f * pl, 0.0f), 32767.0f);
        float x2 = fminf(fmaxf(pc + 0.5f * pl, 0.0f), 32767.0f);
        float sc = sc2.x;
        if (x2 - x1 + 1.0f < 8.0f) sc = 0.0f;
        unsigned u = __float_as_uint(sc);
        key0 = (u & 0x80000000u) ? ~u : (u | 0x80000000u);   // ascending uint == ascending float
        pr.x = x1; pr.y = x2;
    }
    {
        float ctr = (float)(8 * (l + 1) + 4);
        float pc = d02.y * w + ctr;
        float pl = expf(d12.y) * w;
        float x1 = fminf(fmaxf(pc - 0.5f * pl, 0.0f), 32767.0f);
        float x2 = fminf(fmaxf(pc + 0.5f * pl, 0.0f), 32767.0f);
        float sc = sc2.y;
        if (x2 - x1 + 1.0f < 8.0f) sc = 0.0f;
        unsigned u = __float_as_uint(sc);
        key1 = (u & 0x80000000u) ? ~u : (u | 0x80000000u);
        pr.z = x1; pr.w = x2;
    }

    // reference's flat index i = l*NA + a, inverted for descending tie-break
    const unsigned long long p0 =
        ((unsigned long long)key0 << 32) | (unsigned)(0xFFFFFFFFu - (unsigned)(l * NA + a));
    const unsigned long long p1 =
        ((unsigned long long)key1 << 32) | (unsigned)(0xFFFFFFFFu - (unsigned)((l + 1) * NA + a));

    *(ulonglong2*)&packed[b * NSEL + r] = make_ulonglong2(p0, p1);   // 16B, r even
    *(float4*)&prop[b * NSEL + r] = pr;                              // 16B, r even
}

// ---------------- Kernel 2: per-image LDS histogram -> exact kmin -> compact ----------------
// Replaces memset + k_thresh + k_compact (3 nodes -> 1). One 1024-thread block per image.
// Full 16-bit-prefix hist in LDS: 32K u32 words, two u16 counts each (max 40960 < 65536).
// Word layout for bucket k: p=k>>1, word = (p&31)*1024 + (p>>5), half = k&1 -> segment-sum
// reads hist[c*1024+tid] are a 2-way bank alias (free). Crossing-bucket suffix-scan
// semantics identical to the proven k_thresh, so kmin is bit-identical.
__global__ __launch_bounds__(1024, 1) void k_select(const unsigned long long* __restrict__ packed,
                                                    unsigned long long* __restrict__ cand,
                                                    int* __restrict__ gcnt) {
    __shared__ unsigned hist[32768];     // 128 KB
    __shared__ unsigned swsum[16];
    __shared__ unsigned sAfter;
    __shared__ int sSeg;
    __shared__ unsigned skmin;
    __shared__ int sCnt;

    const int tid = threadIdx.x;
    const int lane = tid & 63;
    const int wv = tid >> 6;
    const int b = blockIdx.x;
    const unsigned long long* pk = packed + b * NSEL;

    if (tid == 0) sCnt = 0;
    for (int i = tid; i < 32768; i += 1024) hist[i] = 0;
    __syncthreads();

    // --- pass 1: histogram of 16-bit key prefixes (bucket = packed >> 48) ---
    #pragma unroll
    for (int it = 0; it < NSEL / 2048; ++it) {
        const ulonglong2 pp = *(const ulonglong2*)&pk[(it * 1024 + tid) << 1];
        const unsigned k0 = (unsigned)(pp.x >> 48);
        const unsigned k1 = (unsigned)(pp.y >> 48);
        atomicAdd(&hist[(((k0 >> 1) & 31) << 10) | (k0 >> 6)], 1u << ((k0 & 1) << 4));
        atomicAdd(&hist[(((k1 >> 1) & 31) << 10) | (k1 >> 6)], 1u << ((k1 & 1) << 4));
    }
    __syncthreads();

    // --- segment sums: thread t owns buckets [t*64, t*64+64) ---
    unsigned s = 0;
    #pragma unroll
    for (int c = 0; c < 32; ++c) {
        const unsigned h = hist[(c << 10) + tid];
        s += (h & 0xFFFFu) + (h >> 16);
    }
    // block suffix-scan over 1024 segment sums; find crossing segment
    {
        unsigned inc = s;
        #pragma unroll
        for (int d = 1; d < 64; d <<= 1) {
            unsigned u = (unsigned)__shfl_down((int)inc, d, 64);
            if (lane + d < 64) inc += u;
        }
        if (lane == 0) swsum[wv] = inc;
        __syncthreads();
        if (tid < 16) {
            unsigned t = swsum[tid];
            unsigned winc = t;
            #pragma unroll
            for (int d = 1; d < 16; d <<= 1) {
                unsigned u = (unsigned)__shfl_down((int)winc, d, 64);
                if (tid + d < 16) winc += u;
            }
            swsum[tid] = winc - t;               // sum of waves strictly after tid
        }
        __syncthreads();
        const unsigned glob = inc + swsum[wv];   // suffix including own segment
        if (glob >= (unsigned)PRE2 && (glob - s) < (unsigned)PRE2) { sSeg = tid; sAfter = glob - s; }
    }
    __syncthreads();

    // --- fine scan: wave 0 over crossing segment's 64 buckets ---
    if (wv == 0) {
        const int seg = sSeg;
        const unsigned h = hist[((lane >> 1) << 10) + seg];
        const unsigned v = (lane & 1) ? (h >> 16) : (h & 0xFFFFu);
        unsigned inc = v;
        #pragma unroll
        for (int d = 1; d < 64; d <<= 1) {
            unsigned u = (unsigned)__shfl_down((int)inc, d, 64);
            if (lane + d < 64) inc += u;
        }
        const unsigned glob = inc + sAfter;
        if (glob >= (unsigned)PRE2 && (glob - v) < (unsigned)PRE2)
            skmin = ((unsigned)((seg << 6) + lane)) << 16;
    }
    __syncthreads();
    const unsigned kmin = skmin;

    // --- pass 2: compact (unordered; k_rank reconstructs exact descending order) ---
    #pragma unroll
    for (int it = 0; it < NSEL / 2048; ++it) {
        const ulonglong2 pp = *(const ulonglong2*)&pk[(it * 1024 + tid) << 1];
        const bool pd0 = ((unsigned)(pp.x >> 32) >= kmin);
        const bool pd1 = ((unsigned)(pp.y >> 32) >= kmin);
        const unsigned long long m0 = __ballot(pd0);
        const unsigned long long m1 = __ballot(pd1);
        const int cnt = (int)(__popcll(m0) + __popcll(m1));
        int base = 0;
        if (cnt) {
            if (lane == 0) base = atomicAdd(&sCnt, cnt);
            base = __shfl(base, 0, 64);
            const unsigned long long below = (1ULL << lane) - 1ULL;
            if (pd0) {
                int pos = base + (int)__popcll(m0 & below);
                if (pos < CAND) cand[b * CAND + pos] = pp.x;
            }
            if (pd1) {
                int pos = base + (int)__popcll(m0) + (int)__popcll(m1 & below);
                if (pos < CAND) cand[b * CAND + pos] = pp.y;
            }
        }
    }
    __syncthreads();
    if (tid == 0) gcnt[b] = sCnt;
}

// ---------------- Kernel 3: rank-scatter, LDS-staged ----------------
// rank_i = #{j : key_j > key_i}: exact descending-sort position (keys unique).
__global__ __launch_bounds__(256) void k_rank(const unsigned long long* __restrict__ cand,
                                              const int* __restrict__ gcnt,
                                              const float2* __restrict__ prop,
                                              float2* __restrict__ srt) {
    __shared__ __align__(16) unsigned long long keys[CAND];   // 32 KB
    __shared__ unsigned part[4][64][4];                        // 4 KB partial ranks

    const int b = blockIdx.y;
    const int n0 = gcnt[b];
    const int n = n0 < CAND ? n0 : CAND;
    const int ib = blockIdx.x * 256;
    if (ib >= n) return;                       // uniform per block: safe before syncs

    const int tid = threadIdx.x;
    const int lane = tid & 63;
    const int wv = tid >> 6;
    const unsigned long long* cb = cand + b * CAND;

    // --- stage: coalesced bulk load, zero-pad to multiple of 8 (0 never outranks a real key) ---
    const int nP = (n + 7) & ~7;
    for (int j = tid; j < nP; j += 256)
        keys[j] = (j < n) ? cb[j] : 0ULL;
    __syncthreads();

    // --- my 4 candidates' keys (i = ib + 4*lane + c); reads past n are pad, guarded later ---
    const int i0 = ib + (lane << 2);
    const unsigned long long k0 = keys[i0 + 0];
    const unsigned long long k1 = keys[i0 + 1];
    const unsigned long long k2 = keys[i0 + 2];
    const unsigned long long k3 = keys[i0 + 3];

    // --- wave wv scans j-slice [wv*q, wv*q+q), q even -> 16B-aligned pair reads ---
    const int q = nP >> 2;
    const ulonglong2* keys2 = (const ulonglong2*)keys;
    const int p0 = (wv * q) >> 1;
    const int pn = q >> 1;
    unsigned r0 = 0, r1 = 0, r2 = 0, r3 = 0;
    #pragma unroll 4
    for (int p = 0; p < pn; ++p) {
        ulonglong2 kj = keys2[p0 + p];         // broadcast (all lanes same addr): conflict-free
        r0 += (kj.x > k0); r0 += (kj.y > k0);
        r1 += (kj.x > k1); r1 += (kj.y > k1);
        r2 += (kj.x > k2); r2 += (kj.y > k2);
        r3 += (kj.x > k3); r3 += (kj.y > k3);
    }
    part[wv][lane][0] = r0; part[wv][lane][1] = r1;
    part[wv][lane][2] = r2; part[wv][lane][3] = r3;
    __syncthreads();

    // --- combine partials, decode, gather box, scatter to rank position ---
    const int ig = ib + tid;
    if (ig < n) {
        const int l_ = tid >> 2, c_ = tid & 3;
        unsigned r = part[0][l_][c_] + part[1][l_][c_] + part[2][l_][c_] + part[3][l_][c_];
        if (r < PRE2) {
            unsigned long long k = keys[ig];
            unsigned idx_ = 0xFFFFFFFFu - (unsigned)k;
            unsigned a_ = idx_ % 10u, l2_ = idx_ / 10u;
            srt[b * PRE2 + r] = prop[b * NSEL + (a_ << 12) + l2_];
        }
    }
}

// ---------------- Kernel 4: COLUMN-major suppression mask over top-2048 ----------------
__global__ __launch_bounds__(256) void k_mask(const float2* __restrict__ srt,
                                              unsigned long long* __restrict__ maskT) {
    const int g  = blockIdx.x;          // wi in [4g, 4g+3]
    const int wj = blockIdx.y;
    const int b  = blockIdx.z;
    if (g * 4 > wj) return;             // whole group above diagonal

    __shared__ float2 lj[256];
    const int tid = threadIdx.x;
    lj[tid] = srt[b * PRE2 + (g << 8) + tid];    // suppressor candidates (4 words)
    __syncthreads();

    const int wi = (g << 2) + (tid >> 6);
    if (wi > wj) return;
    const int j = (wj << 6) + (tid & 63);

    float2 pj = srt[b * PRE2 + j];
    float ljn = pj.y - pj.x + 1.0f;
    unsigned long long bits = 0ULL;
    const int lbase = (tid >> 6) * 64;
    const int ibase = wi << 6;
    #pragma unroll 4
    for (int t = 0; t < 64; ++t) {
        float2 pv = lj[lbase + t];
        float inter = fminf(pj.y, pv.y) - fmaxf(pj.x, pv.x) + 1.0f;
        bool sup = false;
        if (inter > 0.0f) {
            float uni = ljn + (pv.y - pv.x + 1.0f) - inter;
            sup = (inter / uni) > 0.7f;          // IEEE div, same rounding as reference
        }
        if ((ibase + t < j) && sup) bits |= (1ULL << t);
    }
    maskT[(size_t)b * TWORDS + (size_t)((wj * (wj + 1) / 2) + wi) * 64 + (tid & 63)] = bits;
}

// ---------------- Kernel 5: single-wave greedy, DEPTH-4 column prefetch pipeline ----------------
// Fixed 16 KB stages (16 VMEM ops each), 4 LDS buffers, counted s_waitcnt vmcnt(48):
// 3 stages stay in flight so each has ~3 windows of compute+greedy to hide latency.
__global__ __launch_bounds__(64, 1) void k_reduce(const unsigned long long* __restrict__ maskT,
                                                  const float2* __restrict__ srt,
                                                  float* __restrict__ out) {
    const int b = blockIdx.x;
    const int lane = threadIdx.x;
    __shared__ unsigned long long colbuf[4][2048];   // 4 x 16 KB
    __shared__ unsigned long long Kl[32];            // kept bitset per window
    __shared__ int sKl[POST_NMS];

    const unsigned long long* mTb = maskT + (size_t)b * TWORDS;

    auto stage = [&](int wv, int buf) {              // fixed 16 KB stage (16 VMEM ops)
        const char* src = (const char*)(mTb + (size_t)(wv * (wv + 1) / 2) * 64) + lane * 16;
        char* dst = (char*)(&colbuf[buf][0]);
        #pragma unroll
        for (int k = 0; k < 16; ++k)
            gload_lds16(src + k * 1024, dst + k * 1024);
    };

    stage(0, 0); stage(1, 1); stage(2, 2); stage(3, 3);   // prologue: 64 ops in flight

    int kept = 0;
    bool done = false;

    for (int w = 0; w < 32 && !done; ++w) {
        // stages w+1..w+3 (48 ops) may stay outstanding; stage w must be complete
        asm volatile("s_waitcnt vmcnt(48)" ::: "memory");
        __builtin_amdgcn_sched_barrier(0);

        const unsigned long long* cw = &colbuf[w & 3][0];
        unsigned long long SUP = 0ULL;
        for (int wi = 0; wi < w; ++wi)
            SUP |= Kl[wi] & cw[(wi << 6) + lane];    // broadcast K read + per-lane col read
        unsigned long long x = cw[(w << 6) + lane];  // within-window suppressor column

        unsigned long long avail = ~__ballot(SUP != 0ULL);
        // retire all LDS reads of this buffer, pin x, THEN reuse the buffer slot for w+4
        asm volatile("s_waitcnt lgkmcnt(0)" ::: "memory");
        __builtin_amdgcn_sched_barrier(0);
        asm volatile("" : "+v"(x));
        {
            int nx = w + 4;
            stage(nx < 31 ? nx : 31, nx & 3);        // nx>=32: dummy re-stage keeps vmcnt invariant
        }

        unsigned long long keptw = 0ULL;
        while (avail) {
            int j = __ffsll((long long)avail) - 1;   // wave-uniform
            if (lane == 0) sKl[kept] = (w << 6) + j;
            kept++; keptw |= (1ULL << j);
            if (kept >= POST_NMS) { done = true; break; }
            unsigned long long supb = __ballot(((x >> j) & 1ULL) != 0ULL);
            avail &= ~supb;
            avail &= ~(1ULL << j);
        }
        if (lane == 0) Kl[w] = keptw;
    }

    __syncthreads();
    for (int t = lane; t < POST_NMS; t += 64) {
        float x1 = 0.0f, x2 = 0.0f;
        if (t < kept) {
            float2 pv = srt[b * PRE2 + sKl[t]];
            x1 = pv.x; x2 = pv.y;
        }
        float* o = out + (size_t)(b * POST_NMS + t) * 3;
        o[0] = (float)b; o[1] = x1; o[2] = x2;
    }
}

extern "C" void kernel_launch(void* const* d_in, const int* in_sizes, int n_in,
                              void* d_out, int out_size, void* d_ws, size_t ws_size,
                              hipStream_t stream) {
    const float* scores = (const float*)d_in[0];
    const float* deltas = (const float*)d_in[1];
    float* out = (float*)d_out;

    char* ws = (char*)d_ws;
    unsigned long long* packed = (unsigned long long*)ws;                   // 1,310,720 B
    float2* prop = (float2*)(ws + 1310720);                                 // 1,310,720 B
    float2* srt  = (float2*)(ws + 2621440);                                 //    65,536 B
    unsigned long long* maskT = (unsigned long long*)(ws + 2686976);        // 1,081,344 B
    unsigned long long* cand  = (unsigned long long*)(ws + 3768320);        //   131,072 B
    int* gcnt                 = (int*)(ws + 3899392);                       //        16 B

    k_prep<<<NB * NSEL / 512, 256, 0, stream>>>(scores, deltas, packed, prop);
    k_select<<<NB, 1024, 0, stream>>>(packed, cand, gcnt);
    k_rank<<<dim3(CAND / 256, NB), 256, 0, stream>>>(cand, gcnt, prop, srt);
    k_mask<<<dim3(8, 32, NB), 256, 0, stream>>>(srt, maskT);
    k_reduce<<<NB, 64, 0, stream>>>(maskT, srt, out);
}